// Round 19
// baseline (321.392 us; speedup 1.0000x reference)
//
#include <hip/hip_runtime.h>
#include <hip/hip_bf16.h>

#define EMBED 512
#define NHEAD 8
#define HDIM  64
#define B_    16
#define U_    1024
#define R_    256
#define S_    32
#define M_    31
#define Q_    (R_ + U_ + S_)   // 1312
#define KV_   (M_ + R_ + U_)   // 1311

#define QROWS  (Q_ * B_)        // 20992
#define KVROWS (KV_ * B_)       // 20976
#define OROWS  (1311 * B_)      // 20976
#define OUT0_ROWS (1280 * B_)   // 20480

#define KVPAD_ROWS 1408         // kv rows padded to 11 tiles of 128
#define KPAD 1408               // VT row length (k padded)
#define MROWSTRIDE 44           // packed-mask row stride (words) = 1408 bits

// exp2-domain scale: 0.125 * log2(e)
#define QSCALE 0.18033688011112042f
// fixed-offset softmax, offset folded into the QK^T accumulator init:
// acc starts at SOFFI, so P = exp2(S) directly; masked S = MASKV (absolute).
#define SOFFI (-16.0f)
#define MASKV (-56.0f)

typedef __attribute__((ext_vector_type(8))) short bf16x8;
typedef __attribute__((ext_vector_type(4))) short short4v;
typedef __attribute__((ext_vector_type(4))) float f32x4;
#define MFMA16(a, b, c) __builtin_amdgcn_mfma_f32_16x16x32_bf16(a, b, c, 0, 0, 0)

typedef unsigned short ushort_t;

// native RTNE f32->bf16 (lowers to v_cvt_pk_bf16_f32 on gfx950)
__device__ __forceinline__ ushort_t f2bf(float x) {
    __hip_bfloat16 h = __float2bfloat16(x);
    return *reinterpret_cast<ushort_t*>(&h);
}
__device__ __forceinline__ float bf2f(ushort_t h) {
    return __uint_as_float((unsigned)h << 16);
}
// raw v_exp_f32 (no OCML denormal fixup)
__device__ __forceinline__ float exp2_raw(float x) {
    return __builtin_amdgcn_exp2f(x);
}

__device__ __forceinline__ void gload_lds16(const void* g, void* l) {
    __builtin_amdgcn_global_load_lds(
        (const __attribute__((address_space(1))) unsigned int*)g,
        (__attribute__((address_space(3))) unsigned int*)l, 16, 0, 0);
}

// ---------------------------------------------------------------------------
// Merged fp32 -> bf16 conversion for all 7 segments + mask bit-packing.
// ---------------------------------------------------------------------------
__global__ __launch_bounds__(256) void cvt_all(
    const float* __restrict__ s0, const float* __restrict__ s1,
    const float* __restrict__ s2, const float* __restrict__ s3,
    const float* __restrict__ s4, const float* __restrict__ s5,
    const float* __restrict__ s6,
    ushort_t* __restrict__ SRC_hi, ushort_t* __restrict__ W_hi,
    const int* __restrict__ am, const int* __restrict__ pm,
    unsigned* __restrict__ am_p, unsigned* __restrict__ pm_p)
{
    int bid = blockIdx.x;
    if (bid >= 5884) {
        const int NA = Q_ * MROWSTRIDE;
        const int NP = B_ * MROWSTRIDE;
        int idx = (bid - 5884) * 256 + threadIdx.x;
        if (idx < NA) {
            int q = idx / MROWSTRIDE, w_ = idx % MROWSTRIDE;
            unsigned bits = 0xFFFFFFFFu;
            if (w_ < 41) {
                bits = 0;
                #pragma unroll 4
                for (int i = 0; i < 32; ++i) {
                    int kg = w_ * 32 + i;
                    int v = (kg < KV_) ? am[(size_t)q * KV_ + kg] : 1;
                    bits |= (unsigned)(v != 0) << i;
                }
            }
            am_p[idx] = bits;
        } else if (idx < NA + NP) {
            int j = idx - NA;
            int bb = j / MROWSTRIDE, w_ = j % MROWSTRIDE;
            unsigned bits = 0xFFFFFFFFu;
            if (w_ < 41) {
                bits = 0;
                #pragma unroll 4
                for (int i = 0; i < 32; ++i) {
                    int kg = w_ * 32 + i;
                    int v = (kg < KV_) ? pm[bb * KV_ + kg] : 1;
                    bits |= (unsigned)(v != 0) << i;
                }
            }
            pm_p[j] = bits;
        }
        return;
    }

    const float* src; ushort_t* hi; int n8;
    if (bid < 4096)      { src = s0; hi = SRC_hi;            n8 = 1048576; }
    else if (bid < 5120) { src = s1; hi = SRC_hi + 8388608;  n8 = 262144; bid -= 4096; }
    else if (bid < 5248) { src = s2; hi = SRC_hi + 10485760; n8 = 32768;  bid -= 5120; }
    else if (bid < 5372) { src = s3; hi = SRC_hi + 10747904; n8 = 31744;  bid -= 5248; }
    else if (bid < 5500) { src = s4; hi = W_hi;              n8 = 32768;  bid -= 5372; }
    else if (bid < 5756) { src = s5; hi = W_hi + 262144;     n8 = 65536;  bid -= 5500; }
    else                 { src = s6; hi = W_hi + 786432;     n8 = 32768;  bid -= 5756; }

    int i = bid * 256 + threadIdx.x;
    if (i >= n8) return;
    const float4* s = (const float4*)(src + (size_t)i * 8);
    float4 a = s[0], b2 = s[1];
    float xs[8] = {a.x, a.y, a.z, a.w, b2.x, b2.y, b2.z, b2.w};
    bf16x8 hv;
    #pragma unroll
    for (int j = 0; j < 8; ++j) hv[j] = (short)f2bf(xs[j]);
    *(bf16x8*)(hi + (size_t)i * 8) = hv;
}

// ---------------------------------------------------------------------------
// MFMA projection GEMM, single-term bf16. 1-D grid with XCD-chunked swizzle:
// wid = (bid&7)*(grid/8) + bid>>3; row-panel-major, N fastest (NCB col
// blocks) so all col-blocks sharing an A-panel are adjacent in one XCD's
// chunk -> A fetched once into that XCD's L2 instead of NCB x from HBM.
// MODE 1: K / V split (NCB=8). MODE 2: fp32 out0 / clipped out1 (NCB=4).
// ---------------------------------------------------------------------------
template<int MODE, int NCB>
__global__ __launch_bounds__(256) void gemm_mfma(
    const ushort_t* __restrict__ A, const ushort_t* __restrict__ W,
    const float* __restrict__ bias, float scale,
    int n0, int n01, int nrows,
    size_t off0, size_t off1, size_t off2,
    void* __restrict__ o0, void* __restrict__ o1, void* __restrict__ o2)
{
    __shared__ __align__(16) ushort_t lA[128][64];
    __shared__ __align__(16) ushort_t lW[128][64];

    const int tid = threadIdx.x;
    const int w   = tid >> 6;
    const int l   = tid & 63;
    const int l15 = l & 15;
    const int l4  = l >> 4;

    const int chunk = gridDim.x >> 3;
    const int wid = (blockIdx.x & 7) * chunk + (blockIdx.x >> 3);
    const int row0 = (wid / NCB) * 128;
    const int col0 = (wid % NCB) * 128;

    const int drow = l >> 3;
    const int sgr  = (l & 7) ^ drow;
    const ushort_t* aptr[4];
    const ushort_t* wptr[4];
    #pragma unroll
    for (int c = 0; c < 4; ++c) {
        int r = row0 + w * 32 + c * 8 + drow;
        int rc = r < nrows ? r : nrows - 1;
        size_t roff;
        if (MODE == 2)      roff = (size_t)rc * EMBED;
        else if (rc < n0)   roff = off0 + (size_t)rc * EMBED;
        else if (rc < n01)  roff = off1 + (size_t)(rc - n0) * EMBED;
        else                roff = off2 + (size_t)(rc - n01) * EMBED;
        aptr[c] = A + roff + sgr * 8;
        int wr = col0 + w * 32 + c * 8 + drow;
        wptr[c] = W + (size_t)wr * EMBED + sgr * 8;
    }

    f32x4 acc[4][4];
    #pragma unroll
    for (int mi = 0; mi < 4; ++mi)
        #pragma unroll
        for (int nj = 0; nj < 4; ++nj) acc[mi][nj] = (f32x4){0.f, 0.f, 0.f, 0.f};

    const int wrow = (w >> 1) * 64;
    const int wcol = (w & 1) * 64;

    for (int t = 0; t < 8; ++t) {
        __syncthreads();
        const int ke = t * 64;
        #pragma unroll
        for (int c = 0; c < 4; ++c) {
            gload_lds16(aptr[c] + ke, &lA[w * 32 + c * 8][0]);
            gload_lds16(wptr[c] + ke, &lW[w * 32 + c * 8][0]);
        }
        __syncthreads();

        #pragma unroll
        for (int kk = 0; kk < 2; ++kk) {
            bf16x8 ah[4], wh[4];
            #pragma unroll
            for (int mi = 0; mi < 4; ++mi) {
                int row = wrow + mi * 16 + l15;
                int g = (((kk * 4 + l4) ^ (l15 & 7))) * 8;
                ah[mi] = *(const bf16x8*)&lA[row][g];
            }
            #pragma unroll
            for (int nj = 0; nj < 4; ++nj) {
                int row = wcol + nj * 16 + l15;
                int g = (((kk * 4 + l4) ^ (l15 & 7))) * 8;
                wh[nj] = *(const bf16x8*)&lW[row][g];
            }
            #pragma unroll
            for (int mi = 0; mi < 4; ++mi)
                #pragma unroll
                for (int nj = 0; nj < 4; ++nj)
                    acc[mi][nj] = MFMA16(ah[mi], wh[nj], acc[mi][nj]);
        }
    }

    #pragma unroll
    for (int nj = 0; nj < 4; ++nj) {
        int gc = col0 + wcol + nj * 16 + l15;
        float bv = bias[gc];
        #pragma unroll
        for (int mi = 0; mi < 4; ++mi) {
            #pragma unroll
            for (int r = 0; r < 4; ++r) {
                int gr = row0 + wrow + mi * 16 + l4 * 4 + r;
                if (gr >= nrows) continue;
                float v = (acc[mi][nj][r] + bv) * scale;
                if (MODE == 1) {
                    if (gc < EMBED)
                        ((ushort_t*)o0)[(size_t)gr * EMBED + gc] = f2bf(v);
                    else
                        ((ushort_t*)o2)[(size_t)gr * EMBED + (gc - EMBED)] = f2bf(v);
                } else {
                    if (gr < OUT0_ROWS)
                        ((float*)o0)[(size_t)gr * EMBED + gc] = v;
                    else if (gr < OROWS)
                        ((float*)o1)[(size_t)(gr - OUT0_ROWS) * EMBED + gc] =
                            fminf(fmaxf(v, -10.f), 10.f);
                }
            }
        }
    }
}

// ---------------------------------------------------------------------------
// FUSED q-projection + V-transpose, XCD-chunked swizzle (3472 = 8 x 434).
// wid < 656:  q-proj block (row0 = (wid>>2)*128, col0 = (wid&3)*128)
// wid >= 656: vtrans block (kt = b2%22, bh = b2/22)
// ---------------------------------------------------------------------------
__global__ __launch_bounds__(256) void fuse_q_vt(
    const ushort_t* __restrict__ SRC, const ushort_t* __restrict__ Wq,
    const float* __restrict__ bq,
    const ushort_t* __restrict__ Vp,
    ushort_t* __restrict__ Q_p, ushort_t* __restrict__ VT)
{
    __shared__ __align__(16) ushort_t SMEM[16384];   // 32 KB
    const int tid = threadIdx.x;
    const int wid = (blockIdx.x & 7) * 434 + (blockIdx.x >> 3);

    if (wid >= 656) {
        // ---------------- vtrans path ----------------
        int b2 = wid - 656;
        const int kt = b2 % 22;
        const int bh = b2 / 22;
        const int b  = bh >> 3, h = bh & 7;
        const int sub = tid >> 3;
        const int g   = tid & 7;
        ushort_t (*Lt)[72] = (ushort_t(*)[72])SMEM;

        #pragma unroll
        for (int p = 0; p < 2; ++p) {
            int k = kt * 64 + p * 32 + sub;
            bf16x8 v;
            if (k < KV_) {
                v = *(const bf16x8*)(Vp + ((size_t)k * B_ + b) * EMBED + h * HDIM + g * 8);
            } else {
                #pragma unroll
                for (int j = 0; j < 8; ++j) v[j] = 0;
            }
            #pragma unroll
            for (int j = 0; j < 8; ++j)
                Lt[g * 8 + j][p * 32 + sub] = (ushort_t)v[j];
        }
        __syncthreads();
        #pragma unroll
        for (int p = 0; p < 2; ++p) {
            int d = p * 32 + sub;
            bf16x8 v = *(const bf16x8*)&Lt[d][g * 8];
            if (d & 8) {
                bf16x8 t;
                #pragma unroll
                for (int j = 0; j < 8; ++j) t[j] = v[j ^ 4];
                v = t;
            }
            *(bf16x8*)(VT + ((size_t)(bh * 64 + d)) * KPAD + kt * 64 + g * 8) = v;
        }
        return;
    }

    // ---------------- q-proj path (1-term GEMM) ----------------
    ushort_t* lA = SMEM;            // [128][64]
    ushort_t* lW = SMEM + 8192;     // [128][64]

    const int w   = tid >> 6;
    const int l   = tid & 63;
    const int l15 = l & 15;
    const int l4  = l >> 4;
    const int row0 = (wid >> 2) * 128;
    const int col0 = (wid & 3) * 128;

    const int drow = l >> 3;
    const int sgr  = (l & 7) ^ drow;
    const ushort_t* aptr[4];
    const ushort_t* wptr[4];
    #pragma unroll
    for (int c = 0; c < 4; ++c) {
        int r = row0 + w * 32 + c * 8 + drow;
        int rc = r < QROWS ? r : QROWS - 1;
        size_t roff;   // q_in = [rc | utter | summ]
        if (rc < R_ * B_)              roff = (size_t)8388608  + (size_t)rc * EMBED;
        else if (rc < (R_ + U_) * B_)  roff = (size_t)(rc - R_ * B_) * EMBED;
        else                           roff = (size_t)10485760 + (size_t)(rc - (R_ + U_) * B_) * EMBED;
        aptr[c] = SRC + roff + sgr * 8;
        int wr = col0 + w * 32 + c * 8 + drow;
        wptr[c] = Wq + (size_t)wr * EMBED + sgr * 8;
    }

    f32x4 acc[4][4];
    #pragma unroll
    for (int mi = 0; mi < 4; ++mi)
        #pragma unroll
        for (int nj = 0; nj < 4; ++nj) acc[mi][nj] = (f32x4){0.f, 0.f, 0.f, 0.f};

    const int wrow = (w >> 1) * 64;
    const int wcol = (w & 1) * 64;

    for (int t = 0; t < 8; ++t) {
        __syncthreads();
        const int ke = t * 64;
        #pragma unroll
        for (int c = 0; c < 4; ++c) {
            gload_lds16(aptr[c] + ke, lA + (w * 32 + c * 8) * 64);
            gload_lds16(wptr[c] + ke, lW + (w * 32 + c * 8) * 64);
        }
        __syncthreads();

        #pragma unroll
        for (int kk = 0; kk < 2; ++kk) {
            bf16x8 ah[4], wh[4];
            #pragma unroll
            for (int mi = 0; mi < 4; ++mi) {
                int row = wrow + mi * 16 + l15;
                int g = (((kk * 4 + l4) ^ (l15 & 7))) * 8;
                ah[mi] = *(const bf16x8*)(lA + row * 64 + g);
            }
            #pragma unroll
            for (int nj = 0; nj < 4; ++nj) {
                int row = wcol + nj * 16 + l15;
                int g = (((kk * 4 + l4) ^ (l15 & 7))) * 8;
                wh[nj] = *(const bf16x8*)(lW + row * 64 + g);
            }
            #pragma unroll
            for (int mi = 0; mi < 4; ++mi)
                #pragma unroll
                for (int nj = 0; nj < 4; ++nj)
                    acc[mi][nj] = MFMA16(ah[mi], wh[nj], acc[mi][nj]);
        }
    }

    #pragma unroll
    for (int nj = 0; nj < 4; ++nj) {
        int gc = col0 + wcol + nj * 16 + l15;
        float bv = bq[gc];
        #pragma unroll
        for (int mi = 0; mi < 4; ++mi) {
            #pragma unroll
            for (int r = 0; r < 4; ++r) {
                int gr = row0 + wrow + mi * 16 + l4 * 4 + r;
                if (gr >= QROWS) continue;
                float v = (acc[mi][nj][r] + bv) * QSCALE;
                Q_p[(size_t)gr * EMBED + gc] = f2bf(v);
            }
        }
    }
}

// ---------------------------------------------------------------------------
// MFMA flash attention, QBLK=128 (8 waves), KVBLK=128 (11 tiles), dbuf LDS.
// XCD-chunked swizzle (1408 = 8 x 176). 1-term QK^T, acc init = -16.
// P in registers; PV A = V^T b64 fragments (conflict-free). 64 KB LDS.
// ---------------------------------------------------------------------------
__global__ __launch_bounds__(512, 4) void attn_mfma(
    const ushort_t* __restrict__ Q_p,
    const ushort_t* __restrict__ Khi_p, const ushort_t* __restrict__ VT,
    const unsigned* __restrict__ am_p, const unsigned* __restrict__ pm_p,
    ushort_t* __restrict__ C_p)
{
    __shared__ __align__(16) ushort_t SM[32768];   // 64 KB
    #define KlAt(buf, row) (SM + (buf) * 8192 + (row) * 64)
    #define VtAt(buf, row) (SM + 16384 + (buf) * 8192 + (row) * 128)

    const int tid = threadIdx.x;
    const int w   = tid >> 6;              // 0..7
    const int l   = tid & 63;
    const int l15 = l & 15;
    const int l4  = l >> 4;

    // --- XCD-chunked work mapping (1408 = 8 * 176, bijective)
    const int wid = (blockIdx.x & 7) * 176 + (blockIdx.x >> 3);
    const int bh  = wid / 11;
    const int xq  = wid - bh * 11;
    const int q0  = xq * 128;
    const int b   = bh >> 3, h = bh & 7;
    const bool qact = (q0 + w * 16) < Q_;  // wave-uniform

    // --- Q fragments (hoisted, single bf16 plane)
    bf16x8 Qf[2];
    {
        int qa = q0 + w * 16 + l15;
        if (qa >= Q_) qa = Q_ - 1;
        size_t base = ((size_t)qa * B_ + b) * EMBED + h * HDIM;
        #pragma unroll
        for (int dh = 0; dh < 2; ++dh)
            Qf[dh] = *(const bf16x8*)(Q_p + base + dh * 32 + l4 * 8);
    }

    // --- row-0-ones A fragment for the sum-MFMA
    bf16x8 ONES;
    #pragma unroll
    for (int j = 0; j < 8; ++j) ONES[j] = (l15 == 0) ? (short)0x3F80 : (short)0;

    // --- mask row pointer (lane owns q row = q0 + w*16 + l15)
    const unsigned* awp;
    {
        int q = q0 + w * 16 + l15;
        if (q >= Q_) q = Q_ - 1;
        awp = am_p + (size_t)q * MROWSTRIDE;
    }
    const unsigned* pwp = pm_p + b * MROWSTRIDE;

    // --- K staging: lane covers tile-row w*8+(l>>3) (and +64), granule l&7
    const int krl = l >> 3;
    const int gsK = (l & 7) ^ krl;
    const ushort_t* kSrc0 =
        Khi_p + ((size_t)(w * 8 + krl) * B_ + b) * EMBED + h * HDIM + gsK * 8;

    // --- V staging: two 4-row chunks (256B rows), granule (l&15)^row&7
    const int vro = l >> 4;                // 0..3
    const int g16 = l & 15;
    const ushort_t* vSrcA =
        VT + ((size_t)(bh * 64 + w * 8 + vro)) * KPAD + ((g16 ^ vro) * 8);
    const ushort_t* vSrcB =
        VT + ((size_t)(bh * 64 + w * 8 + 4 + vro)) * KPAD + ((g16 ^ (4 + vro)) * 8);

    // --- PV fragment geometry (per-lane constants)
    const int gb  = l4 >> 1;
    const int hsw = ((l4 & 1) ^ ((l15 >> 3) & 1)) * 4;
    const int x7  = l15 & 7;

    f32x4 SS = (f32x4){0.f, 0.f, 0.f, 0.f};
    f32x4 O[4];
    #pragma unroll
    for (int dg = 0; dg < 4; ++dg) O[dg] = (f32x4){0.f, 0.f, 0.f, 0.f};

    auto stage = [&](int kbase, int buf) {
        gload_lds16(kSrc0 + (size_t)kbase * B_ * EMBED,        KlAt(buf, w * 8));
        gload_lds16(kSrc0 + (size_t)(kbase + 64) * B_ * EMBED, KlAt(buf, 64 + w * 8));
        gload_lds16(vSrcA + kbase, VtAt(buf, w * 8));
        gload_lds16(vSrcB + kbase, VtAt(buf, w * 8 + 4));
    };

    stage(0, 0);
    __syncthreads();
    int cur = 0;

    for (int kt = 0; kt < 11; ++kt) {
        // --- prefetch next tile into other buffer
        if (kt < 10) stage((kt + 1) * 128, cur ^ 1);

        if (qact) {
            // --- masks: 4 words (128 k), pre-shifted to this lane's k
            uint2 pw0 = *(const uint2*)&pwp[4 * kt];
            uint2 pw1 = *(const uint2*)&pwp[4 * kt + 2];
            uint2 aw0 = *(const uint2*)&awp[4 * kt];
            uint2 aw1 = *(const uint2*)&awp[4 * kt + 2];
            unsigned mm[4];
            mm[0] = (aw0.x | pw0.x) >> (l4 * 4);
            mm[1] = (aw0.y | pw0.y) >> (l4 * 4);
            mm[2] = (aw1.x | pw1.x) >> (l4 * 4);
            mm[3] = (aw1.y | pw1.y) >> (l4 * 4);

            // --- QK^T (swapped, 1-term, acc init = SOFFI)
            f32x4 S[8];
            __builtin_amdgcn_s_setprio(1);
            #pragma unroll
            for (int c = 0; c < 8; ++c) {
                f32x4 acc = (f32x4){SOFFI, SOFFI, SOFFI, SOFFI};
                int krow = c * 16 + l15;
                #pragma unroll
                for (int dh = 0; dh < 2; ++dh) {
                    int gr = ((dh * 4 + l4) ^ x7) * 8;
                    bf16x8 Bh = *(const bf16x8*)(KlAt(cur, krow) + gr);
                    acc = MFMA16(Bh, Qf[dh], acc);
                }
                S[c] = acc;
            }
            __builtin_amdgcn_s_setprio(0);

            // --- mask + P = exp2(S), packed in registers as PV B-fragments
            bf16x8 PB[4];
            #pragma unroll
            for (int c = 0; c < 8; ++c) {
                unsigned mw = mm[c >> 1];
                int sh = (c & 1) << 4;
                #pragma unroll
                for (int r = 0; r < 4; ++r) {
                    float s = ((mw >> (sh + r)) & 1) ? MASKV : S[c][r];
                    PB[c >> 1][(c & 1) * 4 + r] = (short)f2bf(exp2_raw(s));
                }
            }

            // --- sum-MFMA (denominator) + PV (A = V^T fragment, same sigma)
            __builtin_amdgcn_s_setprio(1);
            SS = MFMA16(ONES, PB[0], SS);
            SS = MFMA16(ONES, PB[1], SS);
            SS = MFMA16(ONES, PB[2], SS);
            SS = MFMA16(ONES, PB[3], SS);
            #pragma unroll
            for (int kh = 0; kh < 4; ++kh) {
                #pragma unroll
                for (int dg = 0; dg < 4; ++dg) {
                    int rw = dg * 16 + l15;
                    const ushort_t* vrow = VtAt(cur, rw);
                    int G0 = (kh * 4 + gb) ^ x7;
                    int G1 = (kh * 4 + 2 + gb) ^ x7;
                    union { bf16x8 v8; short4v h2[2]; } u;
                    u.h2[0] = *(const short4v*)(vrow + G0 * 8 + hsw);
                    u.h2[1] = *(const short4v*)(vrow + G1 * 8 + hsw);
                    O[dg] = MFMA16(u.v8, PB[kh], O[dg]);
                }
            }
            __builtin_amdgcn_s_setprio(0);
        }

        __syncthreads();
        cur ^= 1;
    }

    // --- epilogue: normalize, transpose O^T through freed LDS, write coalesced
    if (!qact) return;
    float sT  = __shfl(SS[0], l15, 64);
    float inv = 1.f / sT;

    float* TB = ((float*)SM) + w * 1024;       // per-wave [16][64] f32, granule-XOR
    #pragma unroll
    for (int dg = 0; dg < 4; ++dg) {
        f32x4 vv;
        #pragma unroll
        for (int r = 0; r < 4; ++r) vv[r] = O[dg][r] * inv;
        int gsw = (dg * 4 + l4) ^ (l15 & 7);
        *(f32x4*)(TB + l15 * 64 + gsw * 4) = vv;
    }

    #pragma unroll
    for (int qq = 0; qq < 16; ++qq) {
        int q = q0 + w * 16 + qq;
        if (q >= Q_) break;
        float v = TB[qq * 64 + (((l >> 2) ^ (qq & 7)) * 4) + (l & 3)];
        size_t off = ((size_t)q * B_ + b) * EMBED + h * HDIM + l;
        C_p[off] = f2bf(v);
    }
    #undef KlAt
    #undef VtAt
}

// ---------------------------------------------------------------------------
extern "C" void kernel_launch(void* const* d_in, const int* in_sizes, int n_in,
                              void* d_out, int out_size, void* d_ws, size_t ws_size,
                              hipStream_t stream) {
    const float* utter = (const float*)d_in[0];
    const float* rctx  = (const float*)d_in[1];
    const float* summ  = (const float*)d_in[2];
    const float* mem   = (const float*)d_in[3];
    const int* amask   = (const int*)d_in[4];
    const int* pmask   = (const int*)d_in[5];
    const float* Wq  = (const float*)d_in[6];
    const float* bq  = (const float*)d_in[7];
    const float* Wkv = (const float*)d_in[8];
    const float* bkv = (const float*)d_in[9];
    const float* Wo  = (const float*)d_in[10];
    const float* bo  = (const float*)d_in[11];

    const size_t UT_OFF = 0;
    const size_t RC_OFF = 8388608;
    const size_t SM_OFF = 10485760;
    const size_t MM_OFF = 10747904;
    const size_t SRC_N  = 11001856;
    const size_t WQ_OFF = 0, WKV_OFF = 262144, WO_OFF = 786432;
    const size_t W_N = 1048576;
    const size_t KVPLANE = (size_t)KVPAD_ROWS * B_ * EMBED;   // 11,534,336

    ushort_t* p = (ushort_t*)d_ws;
    ushort_t* SRC_hi = p;                p += SRC_N;
    ushort_t* Wp_hi  = p;                p += W_N;
    ushort_t* Q_p    = p;                p += (size_t)QROWS * EMBED;
    ushort_t* Khi_p  = p;                p += KVPLANE;
    ushort_t* VT_p   = p;                p += KVPLANE;
    ushort_t* Vp     = p;                p += KVPLANE;
    ushort_t* C_p    = p;                p += (size_t)QROWS * EMBED;
    unsigned* am_p   = (unsigned*)p;     p += (size_t)2 * KVPAD_ROWS * MROWSTRIDE;
    unsigned* pm_p   = (unsigned*)p;     p += (size_t)2 * B_ * MROWSTRIDE;

    float* out0 = (float*)d_out;
    float* out1 = out0 + (size_t)OUT0_ROWS * EMBED;

    dim3 blk(256);

    // merged bf16 conversion + mask packing (one launch; 5884 + 229 blocks)
    cvt_all<<<dim3(6113), blk, 0, stream>>>(
        utter, rctx, summ, mem, Wq, Wkv, Wo,
        SRC_hi, Wp_hi, amask, pmask, am_p, pm_p);

    // kv projection (1-term), XCD-chunked 1-D grid: 1312 = 8 x 164, NCB=8
    gemm_mfma<1, 8><<<dim3(1312), blk, 0, stream>>>(
        SRC_hi, Wp_hi + WKV_OFF, bkv, 1.0f,
        M_ * B_, (M_ + R_) * B_, KVROWS, MM_OFF, RC_OFF, UT_OFF,
        Khi_p, nullptr, Vp);

    // fused q-projection + V transpose, XCD-chunked (3472 = 8 x 434)
    fuse_q_vt<<<dim3(3472), blk, 0, stream>>>(
        SRC_hi, Wp_hi + WQ_OFF, bq, Vp, Q_p, VT_p);

    // attention: 1-D grid, XCD-chunked block->work swizzle (1408 = 8 x 176)
    attn_mfma<<<dim3(1408), dim3(512), 0, stream>>>(
        Q_p, Khi_p, VT_p, am_p, pm_p, C_p);

    // out projection (1-term) + clip/split, XCD-chunked: 656 = 8 x 82, NCB=4
    gemm_mfma<2, 4><<<dim3(656), blk, 0, stream>>>(
        C_p, Wp_hi + WO_OFF, bo, 1.0f,
        QROWS, QROWS, QROWS, 0, 0, 0,
        out0, out1, nullptr);
}

// Round 20
// 266.362 us; speedup vs baseline: 1.2066x; 1.2066x over previous
//
#include <hip/hip_runtime.h>
#include <hip/hip_bf16.h>

#define EMBED 512
#define NHEAD 8
#define HDIM  64
#define B_    16
#define U_    1024
#define R_    256
#define S_    32
#define M_    31
#define Q_    (R_ + U_ + S_)   // 1312
#define KV_   (M_ + R_ + U_)   // 1311

#define QROWS  (Q_ * B_)        // 20992
#define KVROWS (KV_ * B_)       // 20976
#define OROWS  (1311 * B_)      // 20976
#define OUT0_ROWS (1280 * B_)   // 20480

#define KVPAD_ROWS 1408         // kv rows padded to 11 tiles of 128
#define KPAD 1408               // VT row length (k padded)
#define MROWSTRIDE 44           // packed-mask row stride (words) = 1408 bits

// exp2-domain scale: 0.125 * log2(e)
#define QSCALE 0.18033688011112042f
// fixed-offset softmax, offset folded into the QK^T accumulator init:
// acc starts at SOFFI, so P = exp2(S) directly; masked S = MASKV (absolute).
#define SOFFI (-16.0f)
#define MASKV (-56.0f)

typedef __attribute__((ext_vector_type(8))) short bf16x8;
typedef __attribute__((ext_vector_type(4))) short short4v;
typedef __attribute__((ext_vector_type(4))) float f32x4;
#define MFMA16(a, b, c) __builtin_amdgcn_mfma_f32_16x16x32_bf16(a, b, c, 0, 0, 0)

typedef unsigned short ushort_t;

// native RTNE f32->bf16 (lowers to v_cvt_pk_bf16_f32 on gfx950)
__device__ __forceinline__ ushort_t f2bf(float x) {
    __hip_bfloat16 h = __float2bfloat16(x);
    return *reinterpret_cast<ushort_t*>(&h);
}
__device__ __forceinline__ float bf2f(ushort_t h) {
    return __uint_as_float((unsigned)h << 16);
}
// raw v_exp_f32 (no OCML denormal fixup)
__device__ __forceinline__ float exp2_raw(float x) {
    return __builtin_amdgcn_exp2f(x);
}

__device__ __forceinline__ void gload_lds16(const void* g, void* l) {
    __builtin_amdgcn_global_load_lds(
        (const __attribute__((address_space(1))) unsigned int*)g,
        (__attribute__((address_space(3))) unsigned int*)l, 16, 0, 0);
}

// ---------------------------------------------------------------------------
// Merged fp32 -> bf16 conversion for all 7 segments + mask bit-packing.
// ---------------------------------------------------------------------------
__global__ __launch_bounds__(256) void cvt_all(
    const float* __restrict__ s0, const float* __restrict__ s1,
    const float* __restrict__ s2, const float* __restrict__ s3,
    const float* __restrict__ s4, const float* __restrict__ s5,
    const float* __restrict__ s6,
    ushort_t* __restrict__ SRC_hi, ushort_t* __restrict__ W_hi,
    const int* __restrict__ am, const int* __restrict__ pm,
    unsigned* __restrict__ am_p, unsigned* __restrict__ pm_p)
{
    int bid = blockIdx.x;
    if (bid >= 5884) {
        const int NA = Q_ * MROWSTRIDE;
        const int NP = B_ * MROWSTRIDE;
        int idx = (bid - 5884) * 256 + threadIdx.x;
        if (idx < NA) {
            int q = idx / MROWSTRIDE, w_ = idx % MROWSTRIDE;
            unsigned bits = 0xFFFFFFFFu;
            if (w_ < 41) {
                bits = 0;
                #pragma unroll 4
                for (int i = 0; i < 32; ++i) {
                    int kg = w_ * 32 + i;
                    int v = (kg < KV_) ? am[(size_t)q * KV_ + kg] : 1;
                    bits |= (unsigned)(v != 0) << i;
                }
            }
            am_p[idx] = bits;
        } else if (idx < NA + NP) {
            int j = idx - NA;
            int bb = j / MROWSTRIDE, w_ = j % MROWSTRIDE;
            unsigned bits = 0xFFFFFFFFu;
            if (w_ < 41) {
                bits = 0;
                #pragma unroll 4
                for (int i = 0; i < 32; ++i) {
                    int kg = w_ * 32 + i;
                    int v = (kg < KV_) ? pm[bb * KV_ + kg] : 1;
                    bits |= (unsigned)(v != 0) << i;
                }
            }
            pm_p[j] = bits;
        }
        return;
    }

    const float* src; ushort_t* hi; int n8;
    if (bid < 4096)      { src = s0; hi = SRC_hi;            n8 = 1048576; }
    else if (bid < 5120) { src = s1; hi = SRC_hi + 8388608;  n8 = 262144; bid -= 4096; }
    else if (bid < 5248) { src = s2; hi = SRC_hi + 10485760; n8 = 32768;  bid -= 5120; }
    else if (bid < 5372) { src = s3; hi = SRC_hi + 10747904; n8 = 31744;  bid -= 5248; }
    else if (bid < 5500) { src = s4; hi = W_hi;              n8 = 32768;  bid -= 5372; }
    else if (bid < 5756) { src = s5; hi = W_hi + 262144;     n8 = 65536;  bid -= 5500; }
    else                 { src = s6; hi = W_hi + 786432;     n8 = 32768;  bid -= 5756; }

    int i = bid * 256 + threadIdx.x;
    if (i >= n8) return;
    const float4* s = (const float4*)(src + (size_t)i * 8);
    float4 a = s[0], b2 = s[1];
    float xs[8] = {a.x, a.y, a.z, a.w, b2.x, b2.y, b2.z, b2.w};
    bf16x8 hv;
    #pragma unroll
    for (int j = 0; j < 8; ++j) hv[j] = (short)f2bf(xs[j]);
    *(bf16x8*)(hi + (size_t)i * 8) = hv;
}

// ---------------------------------------------------------------------------
// MFMA projection GEMM, single-term bf16 (round-18 form: 2-D grid, natural
// dispatch; A re-reads are L3-served so no swizzle is needed or helpful).
// MODE 1: K / V split. MODE 2: fp32 out0 / clipped out1 (row split).
// ---------------------------------------------------------------------------
template<int MODE>
__global__ __launch_bounds__(256) void gemm_mfma(
    const ushort_t* __restrict__ A, const ushort_t* __restrict__ W,
    const float* __restrict__ bias, float scale,
    int n0, int n01, int nrows,
    size_t off0, size_t off1, size_t off2,
    void* __restrict__ o0, void* __restrict__ o1, void* __restrict__ o2)
{
    __shared__ __align__(16) ushort_t lA[128][64];
    __shared__ __align__(16) ushort_t lW[128][64];

    const int tid = threadIdx.x;
    const int w   = tid >> 6;
    const int l   = tid & 63;
    const int l15 = l & 15;
    const int l4  = l >> 4;
    const int row0 = blockIdx.x * 128;
    const int col0 = blockIdx.y * 128;

    const int drow = l >> 3;
    const int sgr  = (l & 7) ^ drow;
    const ushort_t* aptr[4];
    const ushort_t* wptr[4];
    #pragma unroll
    for (int c = 0; c < 4; ++c) {
        int r = row0 + w * 32 + c * 8 + drow;
        int rc = r < nrows ? r : nrows - 1;
        size_t roff;
        if (MODE == 2)      roff = (size_t)rc * EMBED;
        else if (rc < n0)   roff = off0 + (size_t)rc * EMBED;
        else if (rc < n01)  roff = off1 + (size_t)(rc - n0) * EMBED;
        else                roff = off2 + (size_t)(rc - n01) * EMBED;
        aptr[c] = A + roff + sgr * 8;
        int wr = col0 + w * 32 + c * 8 + drow;
        wptr[c] = W + (size_t)wr * EMBED + sgr * 8;
    }

    f32x4 acc[4][4];
    #pragma unroll
    for (int mi = 0; mi < 4; ++mi)
        #pragma unroll
        for (int nj = 0; nj < 4; ++nj) acc[mi][nj] = (f32x4){0.f, 0.f, 0.f, 0.f};

    const int wrow = (w >> 1) * 64;
    const int wcol = (w & 1) * 64;

    for (int t = 0; t < 8; ++t) {
        __syncthreads();
        const int ke = t * 64;
        #pragma unroll
        for (int c = 0; c < 4; ++c) {
            gload_lds16(aptr[c] + ke, &lA[w * 32 + c * 8][0]);
            gload_lds16(wptr[c] + ke, &lW[w * 32 + c * 8][0]);
        }
        __syncthreads();

        #pragma unroll
        for (int kk = 0; kk < 2; ++kk) {
            bf16x8 ah[4], wh[4];
            #pragma unroll
            for (int mi = 0; mi < 4; ++mi) {
                int row = wrow + mi * 16 + l15;
                int g = (((kk * 4 + l4) ^ (l15 & 7))) * 8;
                ah[mi] = *(const bf16x8*)&lA[row][g];
            }
            #pragma unroll
            for (int nj = 0; nj < 4; ++nj) {
                int row = wcol + nj * 16 + l15;
                int g = (((kk * 4 + l4) ^ (l15 & 7))) * 8;
                wh[nj] = *(const bf16x8*)&lW[row][g];
            }
            #pragma unroll
            for (int mi = 0; mi < 4; ++mi)
                #pragma unroll
                for (int nj = 0; nj < 4; ++nj)
                    acc[mi][nj] = MFMA16(ah[mi], wh[nj], acc[mi][nj]);
        }
    }

    #pragma unroll
    for (int nj = 0; nj < 4; ++nj) {
        int gc = col0 + wcol + nj * 16 + l15;
        float bv = bias[gc];
        #pragma unroll
        for (int mi = 0; mi < 4; ++mi) {
            #pragma unroll
            for (int r = 0; r < 4; ++r) {
                int gr = row0 + wrow + mi * 16 + l4 * 4 + r;
                if (gr >= nrows) continue;
                float v = (acc[mi][nj][r] + bv) * scale;
                if (MODE == 1) {
                    if (gc < EMBED)
                        ((ushort_t*)o0)[(size_t)gr * EMBED + gc] = f2bf(v);
                    else
                        ((ushort_t*)o2)[(size_t)gr * EMBED + (gc - EMBED)] = f2bf(v);
                } else {
                    if (gr < OUT0_ROWS)
                        ((float*)o0)[(size_t)gr * EMBED + gc] = v;
                    else if (gr < OROWS)
                        ((float*)o1)[(size_t)(gr - OUT0_ROWS) * EMBED + gc] =
                            fminf(fmaxf(v, -10.f), 10.f);
                }
            }
        }
    }
}

// ---------------------------------------------------------------------------
// FUSED q-projection + V-transpose (round-18 form: natural dispatch).
// bid < 656:  q-proj block (row0 = (bid>>2)*128, col0 = (bid&3)*128)
// bid >= 656: vtrans block (kt = b2%22, bh = b2/22)
// ---------------------------------------------------------------------------
__global__ __launch_bounds__(256) void fuse_q_vt(
    const ushort_t* __restrict__ SRC, const ushort_t* __restrict__ Wq,
    const float* __restrict__ bq,
    const ushort_t* __restrict__ Vp,
    ushort_t* __restrict__ Q_p, ushort_t* __restrict__ VT)
{
    __shared__ __align__(16) ushort_t SMEM[16384];   // 32 KB
    const int tid = threadIdx.x;

    if (blockIdx.x >= 656) {
        // ---------------- vtrans path ----------------
        int b2 = blockIdx.x - 656;
        const int kt = b2 % 22;
        const int bh = b2 / 22;
        const int b  = bh >> 3, h = bh & 7;
        const int sub = tid >> 3;
        const int g   = tid & 7;
        ushort_t (*Lt)[72] = (ushort_t(*)[72])SMEM;

        #pragma unroll
        for (int p = 0; p < 2; ++p) {
            int k = kt * 64 + p * 32 + sub;
            bf16x8 v;
            if (k < KV_) {
                v = *(const bf16x8*)(Vp + ((size_t)k * B_ + b) * EMBED + h * HDIM + g * 8);
            } else {
                #pragma unroll
                for (int j = 0; j < 8; ++j) v[j] = 0;
            }
            #pragma unroll
            for (int j = 0; j < 8; ++j)
                Lt[g * 8 + j][p * 32 + sub] = (ushort_t)v[j];
        }
        __syncthreads();
        #pragma unroll
        for (int p = 0; p < 2; ++p) {
            int d = p * 32 + sub;
            bf16x8 v = *(const bf16x8*)&Lt[d][g * 8];
            if (d & 8) {
                bf16x8 t;
                #pragma unroll
                for (int j = 0; j < 8; ++j) t[j] = v[j ^ 4];
                v = t;
            }
            *(bf16x8*)(VT + ((size_t)(bh * 64 + d)) * KPAD + kt * 64 + g * 8) = v;
        }
        return;
    }

    // ---------------- q-proj path (1-term GEMM) ----------------
    ushort_t* lA = SMEM;            // [128][64]
    ushort_t* lW = SMEM + 8192;     // [128][64]

    const int w   = tid >> 6;
    const int l   = tid & 63;
    const int l15 = l & 15;
    const int l4  = l >> 4;
    const int row0 = (blockIdx.x >> 2) * 128;
    const int col0 = (blockIdx.x & 3) * 128;

    const int drow = l >> 3;
    const int sgr  = (l & 7) ^ drow;
    const ushort_t* aptr[4];
    const ushort_t* wptr[4];
    #pragma unroll
    for (int c = 0; c < 4; ++c) {
        int r = row0 + w * 32 + c * 8 + drow;
        int rc = r < QROWS ? r : QROWS - 1;
        size_t roff;   // q_in = [rc | utter | summ]
        if (rc < R_ * B_)              roff = (size_t)8388608  + (size_t)rc * EMBED;
        else if (rc < (R_ + U_) * B_)  roff = (size_t)(rc - R_ * B_) * EMBED;
        else                           roff = (size_t)10485760 + (size_t)(rc - (R_ + U_) * B_) * EMBED;
        aptr[c] = SRC + roff + sgr * 8;
        int wr = col0 + w * 32 + c * 8 + drow;
        wptr[c] = Wq + (size_t)wr * EMBED + sgr * 8;
    }

    f32x4 acc[4][4];
    #pragma unroll
    for (int mi = 0; mi < 4; ++mi)
        #pragma unroll
        for (int nj = 0; nj < 4; ++nj) acc[mi][nj] = (f32x4){0.f, 0.f, 0.f, 0.f};

    const int wrow = (w >> 1) * 64;
    const int wcol = (w & 1) * 64;

    for (int t = 0; t < 8; ++t) {
        __syncthreads();
        const int ke = t * 64;
        #pragma unroll
        for (int c = 0; c < 4; ++c) {
            gload_lds16(aptr[c] + ke, lA + (w * 32 + c * 8) * 64);
            gload_lds16(wptr[c] + ke, lW + (w * 32 + c * 8) * 64);
        }
        __syncthreads();

        #pragma unroll
        for (int kk = 0; kk < 2; ++kk) {
            bf16x8 ah[4], wh[4];
            #pragma unroll
            for (int mi = 0; mi < 4; ++mi) {
                int row = wrow + mi * 16 + l15;
                int g = (((kk * 4 + l4) ^ (l15 & 7))) * 8;
                ah[mi] = *(const bf16x8*)(lA + row * 64 + g);
            }
            #pragma unroll
            for (int nj = 0; nj < 4; ++nj) {
                int row = wcol + nj * 16 + l15;
                int g = (((kk * 4 + l4) ^ (l15 & 7))) * 8;
                wh[nj] = *(const bf16x8*)(lW + row * 64 + g);
            }
            #pragma unroll
            for (int mi = 0; mi < 4; ++mi)
                #pragma unroll
                for (int nj = 0; nj < 4; ++nj)
                    acc[mi][nj] = MFMA16(ah[mi], wh[nj], acc[mi][nj]);
        }
    }

    #pragma unroll
    for (int nj = 0; nj < 4; ++nj) {
        int gc = col0 + wcol + nj * 16 + l15;
        float bv = bq[gc];
        #pragma unroll
        for (int mi = 0; mi < 4; ++mi) {
            #pragma unroll
            for (int r = 0; r < 4; ++r) {
                int gr = row0 + wrow + mi * 16 + l4 * 4 + r;
                if (gr >= QROWS) continue;
                float v = (acc[mi][nj][r] + bv) * QSCALE;
                Q_p[(size_t)gr * EMBED + gc] = f2bf(v);
            }
        }
    }
}

// ---------------------------------------------------------------------------
// MFMA flash attention, QBLK=128 (8 waves), KVBLK=128 (11 tiles), dbuf LDS.
// XCD-chunked swizzle (1408 = 8 x 176) — verified: FETCH 194 -> 34 MB.
// 1-term QK^T, acc init = -16. P in registers; PV A = V^T b64 fragments
// (conflict-free via granule XOR + baked half-swap). 64 KB LDS.
// ---------------------------------------------------------------------------
__global__ __launch_bounds__(512, 4) void attn_mfma(
    const ushort_t* __restrict__ Q_p,
    const ushort_t* __restrict__ Khi_p, const ushort_t* __restrict__ VT,
    const unsigned* __restrict__ am_p, const unsigned* __restrict__ pm_p,
    ushort_t* __restrict__ C_p)
{
    __shared__ __align__(16) ushort_t SM[32768];   // 64 KB
    #define KlAt(buf, row) (SM + (buf) * 8192 + (row) * 64)
    #define VtAt(buf, row) (SM + 16384 + (buf) * 8192 + (row) * 128)

    const int tid = threadIdx.x;
    const int w   = tid >> 6;              // 0..7
    const int l   = tid & 63;
    const int l15 = l & 15;
    const int l4  = l >> 4;

    // --- XCD-chunked work mapping (1408 = 8 * 176, bijective)
    const int wid = (blockIdx.x & 7) * 176 + (blockIdx.x >> 3);
    const int bh  = wid / 11;
    const int xq  = wid - bh * 11;
    const int q0  = xq * 128;
    const int b   = bh >> 3, h = bh & 7;
    const bool qact = (q0 + w * 16) < Q_;  // wave-uniform

    // --- Q fragments (hoisted, single bf16 plane)
    bf16x8 Qf[2];
    {
        int qa = q0 + w * 16 + l15;
        if (qa >= Q_) qa = Q_ - 1;
        size_t base = ((size_t)qa * B_ + b) * EMBED + h * HDIM;
        #pragma unroll
        for (int dh = 0; dh < 2; ++dh)
            Qf[dh] = *(const bf16x8*)(Q_p + base + dh * 32 + l4 * 8);
    }

    // --- row-0-ones A fragment for the sum-MFMA
    bf16x8 ONES;
    #pragma unroll
    for (int j = 0; j < 8; ++j) ONES[j] = (l15 == 0) ? (short)0x3F80 : (short)0;

    // --- mask row pointer (lane owns q row = q0 + w*16 + l15)
    const unsigned* awp;
    {
        int q = q0 + w * 16 + l15;
        if (q >= Q_) q = Q_ - 1;
        awp = am_p + (size_t)q * MROWSTRIDE;
    }
    const unsigned* pwp = pm_p + b * MROWSTRIDE;

    // --- K staging: lane covers tile-row w*8+(l>>3) (and +64), granule l&7
    const int krl = l >> 3;
    const int gsK = (l & 7) ^ krl;
    const ushort_t* kSrc0 =
        Khi_p + ((size_t)(w * 8 + krl) * B_ + b) * EMBED + h * HDIM + gsK * 8;

    // --- V staging: two 4-row chunks (256B rows), granule (l&15)^row&7
    const int vro = l >> 4;                // 0..3
    const int g16 = l & 15;
    const ushort_t* vSrcA =
        VT + ((size_t)(bh * 64 + w * 8 + vro)) * KPAD + ((g16 ^ vro) * 8);
    const ushort_t* vSrcB =
        VT + ((size_t)(bh * 64 + w * 8 + 4 + vro)) * KPAD + ((g16 ^ (4 + vro)) * 8);

    // --- PV fragment geometry (per-lane constants)
    const int gb  = l4 >> 1;
    const int hsw = ((l4 & 1) ^ ((l15 >> 3) & 1)) * 4;
    const int x7  = l15 & 7;

    f32x4 SS = (f32x4){0.f, 0.f, 0.f, 0.f};
    f32x4 O[4];
    #pragma unroll
    for (int dg = 0; dg < 4; ++dg) O[dg] = (f32x4){0.f, 0.f, 0.f, 0.f};

    auto stage = [&](int kbase, int buf) {
        gload_lds16(kSrc0 + (size_t)kbase * B_ * EMBED,        KlAt(buf, w * 8));
        gload_lds16(kSrc0 + (size_t)(kbase + 64) * B_ * EMBED, KlAt(buf, 64 + w * 8));
        gload_lds16(vSrcA + kbase, VtAt(buf, w * 8));
        gload_lds16(vSrcB + kbase, VtAt(buf, w * 8 + 4));
    };

    stage(0, 0);
    __syncthreads();
    int cur = 0;

    for (int kt = 0; kt < 11; ++kt) {
        // --- prefetch next tile into other buffer
        if (kt < 10) stage((kt + 1) * 128, cur ^ 1);

        if (qact) {
            // --- masks: 4 words (128 k), pre-shifted to this lane's k
            uint2 pw0 = *(const uint2*)&pwp[4 * kt];
            uint2 pw1 = *(const uint2*)&pwp[4 * kt + 2];
            uint2 aw0 = *(const uint2*)&awp[4 * kt];
            uint2 aw1 = *(const uint2*)&awp[4 * kt + 2];
            unsigned mm[4];
            mm[0] = (aw0.x | pw0.x) >> (l4 * 4);
            mm[1] = (aw0.y | pw0.y) >> (l4 * 4);
            mm[2] = (aw1.x | pw1.x) >> (l4 * 4);
            mm[3] = (aw1.y | pw1.y) >> (l4 * 4);

            // --- QK^T (swapped, 1-term, acc init = SOFFI)
            f32x4 S[8];
            __builtin_amdgcn_s_setprio(1);
            #pragma unroll
            for (int c = 0; c < 8; ++c) {
                f32x4 acc = (f32x4){SOFFI, SOFFI, SOFFI, SOFFI};
                int krow = c * 16 + l15;
                #pragma unroll
                for (int dh = 0; dh < 2; ++dh) {
                    int gr = ((dh * 4 + l4) ^ x7) * 8;
                    bf16x8 Bh = *(const bf16x8*)(KlAt(cur, krow) + gr);
                    acc = MFMA16(Bh, Qf[dh], acc);
                }
                S[c] = acc;
            }
            __builtin_amdgcn_s_setprio(0);

            // --- mask + P = exp2(S), packed in registers as PV B-fragments
            bf16x8 PB[4];
            #pragma unroll
            for (int c = 0; c < 8; ++c) {
                unsigned mw = mm[c >> 1];
                int sh = (c & 1) << 4;
                #pragma unroll
                for (int r = 0; r < 4; ++r) {
                    float s = ((mw >> (sh + r)) & 1) ? MASKV : S[c][r];
                    PB[c >> 1][(c & 1) * 4 + r] = (short)f2bf(exp2_raw(s));
                }
            }

            // --- sum-MFMA (denominator) + PV (A = V^T fragment, same sigma)
            __builtin_amdgcn_s_setprio(1);
            SS = MFMA16(ONES, PB[0], SS);
            SS = MFMA16(ONES, PB[1], SS);
            SS = MFMA16(ONES, PB[2], SS);
            SS = MFMA16(ONES, PB[3], SS);
            #pragma unroll
            for (int kh = 0; kh < 4; ++kh) {
                #pragma unroll
                for (int dg = 0; dg < 4; ++dg) {
                    int rw = dg * 16 + l15;
                    const ushort_t* vrow = VtAt(cur, rw);
                    int G0 = (kh * 4 + gb) ^ x7;
                    int G1 = (kh * 4 + 2 + gb) ^ x7;
                    union { bf16x8 v8; short4v h2[2]; } u;
                    u.h2[0] = *(const short4v*)(vrow + G0 * 8 + hsw);
                    u.h2[1] = *(const short4v*)(vrow + G1 * 8 + hsw);
                    O[dg] = MFMA16(u.v8, PB[kh], O[dg]);
                }
            }
            __builtin_amdgcn_s_setprio(0);
        }

        __syncthreads();
        cur ^= 1;
    }

    // --- epilogue: normalize, transpose O^T through freed LDS, write coalesced
    if (!qact) return;
    float sT  = __shfl(SS[0], l15, 64);
    float inv = 1.f / sT;

    float* TB = ((float*)SM) + w * 1024;       // per-wave [16][64] f32, granule-XOR
    #pragma unroll
    for (int dg = 0; dg < 4; ++dg) {
        f32x4 vv;
        #pragma unroll
        for (int r = 0; r < 4; ++r) vv[r] = O[dg][r] * inv;
        int gsw = (dg * 4 + l4) ^ (l15 & 7);
        *(f32x4*)(TB + l15 * 64 + gsw * 4) = vv;
    }

    #pragma unroll
    for (int qq = 0; qq < 16; ++qq) {
        int q = q0 + w * 16 + qq;
        if (q >= Q_) break;
        float v = TB[qq * 64 + (((l >> 2) ^ (qq & 7)) * 4) + (l & 3)];
        size_t off = ((size_t)q * B_ + b) * EMBED + h * HDIM + l;
        C_p[off] = f2bf(v);
    }
    #undef KlAt
    #undef VtAt
}

// ---------------------------------------------------------------------------
extern "C" void kernel_launch(void* const* d_in, const int* in_sizes, int n_in,
                              void* d_out, int out_size, void* d_ws, size_t ws_size,
                              hipStream_t stream) {
    const float* utter = (const float*)d_in[0];
    const float* rctx  = (const float*)d_in[1];
    const float* summ  = (const float*)d_in[2];
    const float* mem   = (const float*)d_in[3];
    const int* amask   = (const int*)d_in[4];
    const int* pmask   = (const int*)d_in[5];
    const float* Wq  = (const float*)d_in[6];
    const float* bq  = (const float*)d_in[7];
    const float* Wkv = (const float*)d_in[8];
    const float* bkv = (const float*)d_in[9];
    const float* Wo  = (const float*)d_in[10];
    const float* bo  = (const float*)d_in[11];

    const size_t UT_OFF = 0;
    const size_t RC_OFF = 8388608;
    const size_t SM_OFF = 10485760;
    const size_t MM_OFF = 10747904;
    const size_t SRC_N  = 11001856;
    const size_t WQ_OFF = 0, WKV_OFF = 262144, WO_OFF = 786432;
    const size_t W_N = 1048576;
    const size_t KVPLANE = (size_t)KVPAD_ROWS * B_ * EMBED;   // 11,534,336

    ushort_t* p = (ushort_t*)d_ws;
    ushort_t* SRC_hi = p;                p += SRC_N;
    ushort_t* Wp_hi  = p;                p += W_N;
    ushort_t* Q_p    = p;                p += (size_t)QROWS * EMBED;
    ushort_t* Khi_p  = p;                p += KVPLANE;
    ushort_t* VT_p   = p;                p += KVPLANE;
    ushort_t* Vp     = p;                p += KVPLANE;
    ushort_t* C_p    = p;                p += (size_t)QROWS * EMBED;
    unsigned* am_p   = (unsigned*)p;     p += (size_t)2 * KVPAD_ROWS * MROWSTRIDE;
    unsigned* pm_p   = (unsigned*)p;     p += (size_t)2 * B_ * MROWSTRIDE;

    float* out0 = (float*)d_out;
    float* out1 = out0 + (size_t)OUT0_ROWS * EMBED;

    dim3 blk(256);

    // merged bf16 conversion + mask packing (one launch; 5884 + 229 blocks)
    cvt_all<<<dim3(6113), blk, 0, stream>>>(
        utter, rctx, summ, mem, Wq, Wkv, Wo,
        SRC_hi, Wp_hi, amask, pmask, am_p, pm_p);

    // kv projection (1-term)
    gemm_mfma<1><<<dim3((KVROWS + 127) / 128, (2 * EMBED) / 128), blk, 0, stream>>>(
        SRC_hi, Wp_hi + WKV_OFF, bkv, 1.0f,
        M_ * B_, (M_ + R_) * B_, KVROWS, MM_OFF, RC_OFF, UT_OFF,
        Khi_p, nullptr, Vp);

    // fused q-projection + V transpose (vtrans hides under the q GEMM)
    fuse_q_vt<<<dim3(656 + 22 * 128), blk, 0, stream>>>(
        SRC_hi, Wp_hi + WQ_OFF, bq, Vp, Q_p, VT_p);

    // attention: 1-D grid, XCD-chunked block->work swizzle (1408 = 8 x 176)
    attn_mfma<<<dim3(1408), dim3(512), 0, stream>>>(
        Q_p, Khi_p, VT_p, am_p, pm_p, C_p);

    // out projection (1-term) + clip/split epilogue
    gemm_mfma<2><<<dim3(QROWS / 128, EMBED / 128), blk, 0, stream>>>(
        C_p, Wp_hi + WO_OFF, bo, 1.0f,
        QROWS, QROWS, QROWS, 0, 0, 0,
        out0, out1, nullptr);
}